// Round 4
// baseline (151.934 us; speedup 1.0000x reference)
//
#include <hip/hip_runtime.h>

// VQ quantizer: N=131072 rows, K=1024 codes, D=10, fp32.
// R4: codebook through SGPRs. Prep kernel writes a 12-float-stride copy of E
// with ms = -0.5*||e||^2 at slot 10 into a device-global (64B-aligned rows).
// Main kernel: each lane owns 4 rows in VGPRs; codes are read via wave-
// uniform scalar loads (readfirstlane-pinned base) -> s_load -> v_fma with
// SGPR operand. Hot loop has NO LDS, NO shuffles, NO VMEM.
// 512 blocks x 512 threads (8 waves): each wave scans K/8=128 codes for the
// block's 256 rows; LDS argmax-merge (ascending wave order, strict > =>
// first-index tie-break, matching argmin). Score = x.e - 0.5||e||^2, same
// fmaf chain order as R1-R3 (absmax 0.0 heritage).

constexpr int N = 131072;
constexpr int K = 1024;
constexpr int D = 10;
constexpr int THREADS = 512;          // 8 waves
constexpr int BLOCKS = 512;           // 2 blocks/CU -> 16 waves/CU = 4/SIMD
constexpr int ROWS_PER_BLOCK = 256;   // N / BLOCKS
constexpr int ROWS_PER_LANE = 4;      // 256 / 64
constexpr int KSPLIT = 8;             // one codebook eighth per wave
constexpr int KPW = K / KSPLIT;       // 128
constexpr int WSTRIDE = 12;           // floats per code row (48B)

__device__ __attribute__((aligned(256))) float g_cb[K * WSTRIDE];

__global__ __launch_bounds__(256) void prep_kernel(const float* __restrict__ E) {
    const int k = blockIdx.x * blockDim.x + threadIdx.x;
    if (k < K) {
        float e[D];
        #pragma unroll
        for (int d = 0; d < D; ++d) e[d] = E[k * D + d];
        float s = 0.f;
        #pragma unroll
        for (int d = 0; d < D; ++d) s = fmaf(e[d], e[d], s);   // same chain as R1-R3
        #pragma unroll
        for (int d = 0; d < D; ++d) g_cb[k * WSTRIDE + d] = e[d];
        g_cb[k * WSTRIDE + D]     = -0.5f * s;
        g_cb[k * WSTRIDE + D + 1] = 0.f;
    }
}

__global__ __launch_bounds__(THREADS, 4) void vq_kernel(
    const float* __restrict__ x,
    const float* __restrict__ E,
    float* __restrict__ out,
    float* __restrict__ loss_out)
{
    __shared__ float sScore[KSPLIT][ROWS_PER_BLOCK];   // 8 KB
    __shared__ int   sIdx[KSPLIT][ROWS_PER_BLOCK];     // 8 KB

    const int tid  = threadIdx.x;
    const int lane = tid & 63;
    const int wave = tid >> 6;
    const int rowBase = blockIdx.x * ROWS_PER_BLOCK;

    // ---- this lane's 4 rows of x -> VGPRs (coalesced: lane-major) ----
    float xr[ROWS_PER_LANE][D];
    #pragma unroll
    for (int j = 0; j < ROWS_PER_LANE; ++j) {
        const float* xp = x + (size_t)(rowBase + lane + 64 * j) * D;
        #pragma unroll
        for (int d = 0; d < D; d += 2) {               // rows 40B apart, 8B aligned
            float2 v = *reinterpret_cast<const float2*>(xp + d);
            xr[j][d]     = v.x;
            xr[j][d + 1] = v.y;
        }
    }

    // ---- hot loop: this wave's eighth of the codebook, codes via SGPRs ----
    // readfirstlane pins the wave-derived base as uniform so the codebook
    // loads become s_load (scalar pipe), leaving VALU purely for FMA/select.
    const int kbase = __builtin_amdgcn_readfirstlane(wave * KPW);

    float best[ROWS_PER_LANE];
    int   bidx[ROWS_PER_LANE];
    #pragma unroll
    for (int j = 0; j < ROWS_PER_LANE; ++j) { best[j] = -3.0e38f; bidx[j] = 0; }

    #pragma unroll 4
    for (int kk = 0; kk < KPW; ++kk) {
        const int k = kbase + kk;
        const float* w = g_cb + k * WSTRIDE;           // wave-uniform address
        const float e0 = w[0], e1 = w[1], e2 = w[2], e3 = w[3], e4 = w[4];
        const float e5 = w[5], e6 = w[6], e7 = w[7], e8 = w[8], e9 = w[9];
        const float ms = w[10];                        // -0.5*||e||^2
        #pragma unroll
        for (int j = 0; j < ROWS_PER_LANE; ++j) {
            float acc = ms;                            // keep R1-R3 fp order
            acc = fmaf(xr[j][0], e0, acc);
            acc = fmaf(xr[j][1], e1, acc);
            acc = fmaf(xr[j][2], e2, acc);
            acc = fmaf(xr[j][3], e3, acc);
            acc = fmaf(xr[j][4], e4, acc);
            acc = fmaf(xr[j][5], e5, acc);
            acc = fmaf(xr[j][6], e6, acc);
            acc = fmaf(xr[j][7], e7, acc);
            acc = fmaf(xr[j][8], e8, acc);
            acc = fmaf(xr[j][9], e9, acc);
            const bool gt = acc > best[j];             // strict >, ascending k
            bidx[j] = gt ? k   : bidx[j];              // v_cndmask with sgpr k
            best[j] = gt ? acc : best[j];
        }
    }

    // ---- publish per-wave winners ----
    #pragma unroll
    for (int j = 0; j < ROWS_PER_LANE; ++j) {
        const int r = lane + 64 * j;
        sScore[wave][r] = best[j];
        sIdx[wave][r]   = bidx[j];
    }
    __syncthreads();

    // ---- merge across waves + epilogue (first 256 threads: 1 row each) ----
    float lsum = 0.f;
    for (int r = tid; r < ROWS_PER_BLOCK; r += THREADS) {
        float bs = sScore[0][r];
        int   bi = sIdx[0][r];
        #pragma unroll
        for (int w = 1; w < KSPLIT; ++w) {
            const float s  = sScore[w][r];
            const int   i2 = sIdx[w][r];
            if (s > bs) { bs = s; bi = i2; }           // ascending wave order
        }
        const float* ep = E   + (size_t)bi * D;        // L2-hot gather
        const float* xp = x   + (size_t)(rowBase + r) * D;
        float*       op = out + (size_t)(rowBase + r) * D;
        #pragma unroll
        for (int d = 0; d < D; d += 2) {
            float2 ev = *reinterpret_cast<const float2*>(ep + d);
            float2 xw = *reinterpret_cast<const float2*>(xp + d);
            const float d0 = xw.x - ev.x;
            const float d1 = xw.y - ev.y;
            lsum = fmaf(d0, d0, lsum);
            lsum = fmaf(d1, d1, lsum);
            float2 o;
            o.x = xw.x + (ev.x - xw.x);                // literal STE expression
            o.y = xw.y + (ev.y - xw.y);
            *reinterpret_cast<float2*>(op + d) = o;
        }
    }

    // ---- loss reduction: wave shuffle -> one atomic per wave ----
    #pragma unroll
    for (int off = 32; off > 0; off >>= 1)
        lsum += __shfl_down(lsum, off, 64);
    if (lane == 0)
        atomicAdd(loss_out, lsum * (1.0f / ((float)N * (float)D)));
}

extern "C" void kernel_launch(void* const* d_in, const int* in_sizes, int n_in,
                              void* d_out, int out_size, void* d_ws, size_t ws_size,
                              hipStream_t stream) {
    const float* x = (const float*)d_in[0];   // encoder_embedding [N, D]
    const float* E = (const float*)d_in[1];   // embedding_weight  [K, D]
    float* out  = (float*)d_out;              // quantized_st [N*D] then loss [1]
    float* loss = out + (size_t)N * D;

    hipMemsetAsync(loss, 0, sizeof(float), stream);       // d_out re-poisoned
    prep_kernel<<<dim3(K / 256), dim3(256), 0, stream>>>(E);
    vq_kernel<<<dim3(BLOCKS), dim3(THREADS), 0, stream>>>(x, E, out, loss);
}